// Round 5
// baseline (273.776 us; speedup 1.0000x reference)
//
#include <hip/hip_runtime.h>

#define BB 2
#define SS 2048
#define EE 768
#define HH 12
#define DKK 64

typedef _Float16 h16;
typedef _Float16 half8 __attribute__((ext_vector_type(8)));
typedef _Float16 h16x4 __attribute__((ext_vector_type(4)));
typedef float f32x4 __attribute__((ext_vector_type(4)));

// ---------------- mask packing: int32 [S,S] -> 1 bit, word = 32 cols ----------------
__global__ void pack_mask_k(const int* __restrict__ mask, unsigned* __restrict__ mp) {
    int idx = blockIdx.x * 256 + threadIdx.x;      // 0 .. S*S/32-1
    int base = idx * 32;
    const int4* m4 = (const int4*)(mask + base);
    unsigned w = 0;
#pragma unroll
    for (int i = 0; i < 8; ++i) {
        int4 v = m4[i];
        if (v.x) w |= 1u << (i * 4 + 0);
        if (v.y) w |= 1u << (i * 4 + 1);
        if (v.z) w |= 1u << (i * 4 + 2);
        if (v.w) w |= 1u << (i * 4 + 3);
    }
    mp[idx] = w;
}

// ---------------- projection GEMM: k/q row-major [b,h,s,d]; v TRANSPOSED [b,h,d,s] ----------------
__launch_bounds__(256)
__global__ void proj_gemm_k(const float* __restrict__ srcK, const float* __restrict__ srcQ,
                            const float* __restrict__ srcV, const float* __restrict__ Wk,
                            const float* __restrict__ bk,
                            h16* __restrict__ kh, h16* __restrict__ qh, h16* __restrict__ vtp) {
    __shared__ h16 As[128 * 64];
    __shared__ h16 Bs[128 * 64];
    const int z = blockIdx.z;
    const float* src = (z == 0) ? srcK : ((z == 1) ? srcQ : srcV);
    const int n0 = blockIdx.x * 128, m0 = blockIdx.y * 128;
    const int tid = threadIdx.x, lane = tid & 63, wid = tid >> 6;
    const int wr = wid >> 1, wc = wid & 1;
    f32x4 acc[4][4] = {};

    for (int k0 = 0; k0 < EE; k0 += 64) {
#pragma unroll
        for (int it = 0; it < 4; ++it) {
            int e8 = it * 256 + tid;          // 0..1023 granules of 8 elems
            int row = e8 >> 3, g = e8 & 7;
            const float* pa = src + (m0 + row) * EE + k0 + g * 8;
            const float* pb = Wk + (n0 + row) * EE + k0 + g * 8;
            float4 a0 = *(const float4*)pa, a1 = *(const float4*)(pa + 4);
            float4 b0 = *(const float4*)pb, b1 = *(const float4*)(pb + 4);
            half8 ha = {(h16)a0.x, (h16)a0.y, (h16)a0.z, (h16)a0.w,
                        (h16)a1.x, (h16)a1.y, (h16)a1.z, (h16)a1.w};
            half8 hb = {(h16)b0.x, (h16)b0.y, (h16)b0.z, (h16)b0.w,
                        (h16)b1.x, (h16)b1.y, (h16)b1.z, (h16)b1.w};
            int sw = (g ^ (row & 7)) << 4;
            *(half8*)((char*)As + row * 128 + sw) = ha;
            *(half8*)((char*)Bs + row * 128 + sw) = hb;
        }
        __syncthreads();
#pragma unroll
        for (int ks = 0; ks < 2; ++ks) {
            half8 a[4], b[4];
#pragma unroll
            for (int rf = 0; rf < 4; ++rf) {
                int row = wr * 64 + rf * 16 + (lane & 15);
                int g = (ks * 4 + (lane >> 4)) ^ (row & 7);
                a[rf] = *(const half8*)((const char*)As + row * 128 + (g << 4));
            }
#pragma unroll
            for (int cf = 0; cf < 4; ++cf) {
                int row = wc * 64 + cf * 16 + (lane & 15);
                int g = (ks * 4 + (lane >> 4)) ^ (row & 7);
                b[cf] = *(const half8*)((const char*)Bs + row * 128 + (g << 4));
            }
#pragma unroll
            for (int rf = 0; rf < 4; ++rf)
#pragma unroll
                for (int cf = 0; cf < 4; ++cf)
                    acc[rf][cf] = __builtin_amdgcn_mfma_f32_16x16x32_f16(a[rf], b[cf], acc[rf][cf], 0, 0, 0);
        }
        __syncthreads();
    }
    if (z == 2) {
        // V: write transposed vt[(b*H+h)*64 + d][s], 4 consecutive s packed
#pragma unroll
        for (int rf = 0; rf < 4; ++rf)
#pragma unroll
            for (int cf = 0; cf < 4; ++cf) {
                int n = n0 + wc * 64 + cf * 16 + (lane & 15);
                float bias = bk[n];
                int h = n >> 6, d = n & 63;
                int mb = m0 + wr * 64 + rf * 16 + (lane >> 4) * 4;
                int b = mb >> 11, s = mb & 2047;
                h16x4 pv = {(h16)(acc[rf][cf][0] + bias), (h16)(acc[rf][cf][1] + bias),
                            (h16)(acc[rf][cf][2] + bias), (h16)(acc[rf][cf][3] + bias)};
                *(h16x4*)(vtp + ((long)((b * HH + h) * 64 + d)) * SS + s) = pv;
            }
    } else {
        h16* dst = (z == 0) ? kh : qh;
#pragma unroll
        for (int rf = 0; rf < 4; ++rf)
#pragma unroll
            for (int cf = 0; cf < 4; ++cf) {
                int n = n0 + wc * 64 + cf * 16 + (lane & 15);
                float bias = bk[n];
                int h = n >> 6, d = n & 63;
#pragma unroll
                for (int j = 0; j < 4; ++j) {
                    int m = m0 + wr * 64 + rf * 16 + (lane >> 4) * 4 + j;
                    int b = m >> 11, s = m & 2047;
                    dst[(((long)(b * HH + h) * SS + s) << 6) + d] = (h16)(acc[rf][cf][j] + bias);
                }
            }
    }
}

// ---------------- flash attention helpers ----------------
__device__ __forceinline__ void qkt8(const half8* kf, const half8& qf0, const half8& qf1,
                                     f32x4* s) {
    __builtin_amdgcn_s_setprio(1);
#pragma unroll
    for (int cf = 0; cf < 4; ++cf) {
        f32x4 z = {};
        z = __builtin_amdgcn_mfma_f32_16x16x32_f16(kf[2 * cf], qf0, z, 0, 0, 0);
        z = __builtin_amdgcn_mfma_f32_16x16x32_f16(kf[2 * cf + 1], qf1, z, 0, 0, 0);
        s[cf] = z;
    }
    __builtin_amdgcn_s_setprio(0);
}

__device__ __forceinline__ void kload(const h16* __restrict__ kbase, int t, half8* kn) {
#pragma unroll
    for (int cf = 0; cf < 4; ++cf) {
        kn[2 * cf]     = *(const half8*)(kbase + (long)t * 4096 + cf * 1024);
        kn[2 * cf + 1] = *(const half8*)(kbase + (long)t * 4096 + cf * 1024 + 32);
    }
}

__device__ __forceinline__ void vload(const h16* __restrict__ vbase, int t, half8* vr) {
#pragma unroll
    for (int ks = 0; ks < 2; ++ks)
#pragma unroll
        for (int df = 0; df < 4; ++df)
            vr[ks * 4 + df] = *(const half8*)(vbase + t * 64 + (long)df * (16 * SS) + ks * 32);
}

// softmax (per-lane q, defer-max fast path, per-lane lsum partial) + P->LDS + PV
__device__ __forceinline__ void smx_pv(f32x4* s, const half8* vr,
                                       const unsigned long long* __restrict__ mrow, int t,
                                       char* pbase, int l, int g,
                                       f32x4* o, float& m2, float& lsum) {
    // ---- mask + scale into exp2 domain ----
    unsigned long long mw = mrow[t];
    unsigned w0 = (unsigned)mw, w1 = (unsigned)(mw >> 32);
    const float K2 = 8.0f * 1.44269504f;       // sqrt(dk) * log2(e)  (source multiplies!)
    const float C2 = 1e-6f * 1.44269504f;      // masked value in log2 domain
#pragma unroll
    for (int cf = 0; cf < 4; ++cf) {
        unsigned wcb = (cf & 2) ? w1 : w0;
#pragma unroll
        for (int j = 0; j < 4; ++j) {
            unsigned sh = ((cf & 1) << 4) + g * 4 + j;
            s[cf][j] = ((wcb >> sh) & 1u) ? s[cf][j] * K2 : C2;
        }
    }
    // ---- in-lane max over 16 kv values ----
    float pmax = fmaxf(fmaxf(s[0][0], s[0][1]), fmaxf(s[0][2], s[0][3]));
#pragma unroll
    for (int cf = 1; cf < 4; ++cf) {
        float q0 = fmaxf(fmaxf(s[cf][0], s[cf][1]), fmaxf(s[cf][2], s[cf][3]));
        pmax = fmaxf(pmax, q0);
    }
    // ---- slow path only when some lane's max grew past m2+11 ----
    if (!__all(pmax <= m2 + 11.0f)) {
        pmax = fmaxf(pmax, __shfl_xor(pmax, 16));
        pmax = fmaxf(pmax, __shfl_xor(pmax, 32));
        float mnew = fmaxf(m2, pmax);
        float alpha = __builtin_amdgcn_exp2f(m2 - mnew);
#pragma unroll
        for (int df = 0; df < 4; ++df)
#pragma unroll
            for (int j = 0; j < 4; ++j) o[df][j] *= alpha;
        lsum *= alpha;
        m2 = mnew;
    }
    float rs = 0.f;
#pragma unroll
    for (int cf = 0; cf < 4; ++cf)
#pragma unroll
        for (int j = 0; j < 4; ++j) {
            float p = __builtin_amdgcn_exp2f(s[cf][j] - m2);
            s[cf][j] = p;
            rs += p;
        }
    lsum += rs;                                 // per-lane partial; reduced in epilogue
    // ---- P^T -> per-wave LDS, packed b64 stores ----
#pragma unroll
    for (int cf = 0; cf < 4; ++cf) {
        h16x4 pk = {(h16)s[cf][0], (h16)s[cf][1], (h16)s[cf][2], (h16)s[cf][3]};
        int gran = (2 * cf + (g >> 1)) ^ (l & 7);
        *(h16x4*)(pbase + l * 128 + gran * 16 + (g & 1) * 8) = pk;
    }
    // ---- O^T += V^T · P^T ----
#pragma unroll
    for (int ks = 0; ks < 2; ++ks) {
        int gr = (ks * 4 + g) ^ (l & 7);
        half8 pf = *(const half8*)(pbase + l * 128 + gr * 16);
        __builtin_amdgcn_s_setprio(1);
#pragma unroll
        for (int df = 0; df < 4; ++df)
            o[df] = __builtin_amdgcn_mfma_f32_16x16x32_f16(vr[ks * 4 + df], pf, o[df], 0, 0, 0);
        __builtin_amdgcn_s_setprio(0);
    }
}

// 4 independent waves per block (no barriers); QK^T(t+1) pipelined under softmax(t)
__launch_bounds__(256, 3)
__global__ void attn_k(const h16* __restrict__ qh, const h16* __restrict__ kh,
                       const h16* __restrict__ vt, const unsigned long long* __restrict__ mp,
                       h16* __restrict__ xh) {
    __shared__ char Ps[8192];                   // 2KB per wave, private
    const int tid = threadIdx.x;
    const int lane = tid & 63, wid = tid >> 6;
    const int l = lane & 15, g = lane >> 4;
    // XCD-aware swizzle: 768 blocks; each XCD gets 96 consecutive idx = 3 whole heads
    const int bid = blockIdx.x;
    const int idx = (bid & 7) * 96 + (bid >> 3);
    const int q0 = (idx & 31) * 64 + wid * 16;
    const int bh = idx >> 5;
    const long base = (long)bh * SS * DKK;
    const h16* kbase = kh + base + (long)l * DKK + g * 8;
    const h16* vbase = vt + base + (long)l * SS + g * 8;
    char* pbase = Ps + wid * 2048;

    half8 qf0, qf1;
    {
        const h16* qp = qh + base + (long)(q0 + l) * DKK + g * 8;
        qf0 = *(const half8*)qp;
        qf1 = *(const half8*)(qp + 32);
    }
    const unsigned long long* mrow = mp + (long)(q0 + l) * (SS / 64);

    f32x4 o[4] = {};
    float m2 = -INFINITY, lsum = 0.f;
    half8 kA[8], kB[8], vr[8];
    f32x4 sA[4], sB[4];

    kload(kbase, 0, kA);
    qkt8(kA, qf0, qf1, sA);                     // S(0)
    kload(kbase, 1, kB);

    for (int it = 0; it < 16; ++it) {
        int t = 2 * it;
        // --- tile t: sA holds S(t); kB holds K(t+1) ---
        qkt8(kB, qf0, qf1, sB);                 // S(t+1) on MFMA pipe
        vload(vbase, t, vr);                    // V(t)
        kload(kbase, (t + 2) & 31, kA);         // K(t+2)
        smx_pv(sA, vr, mrow, t, pbase, l, g, o, m2, lsum);   // VALU + PV, overlaps
        // --- tile t+1: sB holds S(t+1); kA holds K(t+2) ---
        qkt8(kA, qf0, qf1, sA);                 // S(t+2) (last iter: wasted, harmless)
        vload(vbase, t + 1, vr);
        kload(kbase, (t + 3) & 31, kB);
        smx_pv(sB, vr, mrow, t + 1, pbase, l, g, o, m2, lsum);
    }

    // epilogue: reduce lsum across the 4 g-groups; lane owns q = q0+l
    lsum += __shfl_xor(lsum, 16);
    lsum += __shfl_xor(lsum, 32);
    float inv = 1.0f / lsum;
    int b = bh / HH, h = bh % HH;
    h16* xp = xh + (long)(b * SS + q0 + l) * EE + h * 64 + g * 4;
#pragma unroll
    for (int df = 0; df < 4; ++df) {
        h16x4 v4 = {(h16)(o[df][0] * inv), (h16)(o[df][1] * inv),
                    (h16)(o[df][2] * inv), (h16)(o[df][3] * inv)};
        *(h16x4*)(xp + df * 16) = v4;
    }
}

// ---------------- output GEMM: out = x @ Wo^T + bo (fp32 out) ----------------
__launch_bounds__(256)
__global__ void out_gemm_k(const h16* __restrict__ xh, const float* __restrict__ Wo,
                           const float* __restrict__ bo, float* __restrict__ out) {
    __shared__ h16 As[128 * 64];
    __shared__ h16 Bs[128 * 64];
    const int n0 = blockIdx.x * 128, m0 = blockIdx.y * 128;
    const int tid = threadIdx.x, lane = tid & 63, wid = tid >> 6;
    const int wr = wid >> 1, wc = wid & 1;
    f32x4 acc[4][4] = {};

    for (int k0 = 0; k0 < EE; k0 += 64) {
#pragma unroll
        for (int it = 0; it < 4; ++it) {
            int e8 = it * 256 + tid;
            int row = e8 >> 3, g = e8 & 7;
            half8 ha = *(const half8*)(xh + (m0 + row) * EE + k0 + g * 8);
            const float* pb = Wo + (n0 + row) * EE + k0 + g * 8;
            float4 b0 = *(const float4*)pb, b1 = *(const float4*)(pb + 4);
            half8 hb = {(h16)b0.x, (h16)b0.y, (h16)b0.z, (h16)b0.w,
                        (h16)b1.x, (h16)b1.y, (h16)b1.z, (h16)b1.w};
            int sw = (g ^ (row & 7)) << 4;
            *(half8*)((char*)As + row * 128 + sw) = ha;
            *(half8*)((char*)Bs + row * 128 + sw) = hb;
        }
        __syncthreads();
#pragma unroll
        for (int ks = 0; ks < 2; ++ks) {
            half8 a[4], b[4];
#pragma unroll
            for (int rf = 0; rf < 4; ++rf) {
                int row = wr * 64 + rf * 16 + (lane & 15);
                int g = (ks * 4 + (lane >> 4)) ^ (row & 7);
                a[rf] = *(const half8*)((const char*)As + row * 128 + (g << 4));
            }
#pragma unroll
            for (int cf = 0; cf < 4; ++cf) {
                int row = wc * 64 + cf * 16 + (lane & 15);
                int g = (ks * 4 + (lane >> 4)) ^ (row & 7);
                b[cf] = *(const half8*)((const char*)Bs + row * 128 + (g << 4));
            }
#pragma unroll
            for (int rf = 0; rf < 4; ++rf)
#pragma unroll
                for (int cf = 0; cf < 4; ++cf)
                    acc[rf][cf] = __builtin_amdgcn_mfma_f32_16x16x32_f16(a[rf], b[cf], acc[rf][cf], 0, 0, 0);
        }
        __syncthreads();
    }
#pragma unroll
    for (int rf = 0; rf < 4; ++rf)
#pragma unroll
        for (int cf = 0; cf < 4; ++cf) {
            int n = n0 + wc * 64 + cf * 16 + (lane & 15);
            float bias = bo[n];
#pragma unroll
            for (int j = 0; j < 4; ++j) {
                int m = m0 + wr * 64 + rf * 16 + (lane >> 4) * 4 + j;
                out[(long)m * EE + n] = acc[rf][cf][j] + bias;
            }
        }
}

extern "C" void kernel_launch(void* const* d_in, const int* in_sizes, int n_in,
                              void* d_out, int out_size, void* d_ws, size_t ws_size,
                              hipStream_t stream) {
    const float* key   = (const float*)d_in[0];
    const float* query = (const float*)d_in[1];
    const float* value = (const float*)d_in[2];
    const int*   mask  = (const int*)d_in[3];
    const float* Wk    = (const float*)d_in[4];
    const float* bk    = (const float*)d_in[5];
    const float* Wo    = (const float*)d_in[6];
    const float* bo    = (const float*)d_in[7];

    char* ws = (char*)d_ws;
    h16* qh = (h16*)(ws + 0);
    h16* kh = (h16*)(ws + 6291456);
    h16* vt = (h16*)(ws + 12582912);
    h16* xh = (h16*)(ws + 18874368);
    unsigned* mp = (unsigned*)(ws + 25165824);
    float* out = (float*)d_out;

    hipLaunchKernelGGL(pack_mask_k, dim3(SS * SS / 32 / 256), dim3(256), 0, stream, mask, mp);
    hipLaunchKernelGGL(proj_gemm_k, dim3(EE / 128, BB * SS / 128, 3), dim3(256), 0, stream,
                       key, query, value, Wk, bk, kh, qh, vt);
    hipLaunchKernelGGL(attn_k, dim3(SS / 64 * BB * HH), dim3(256), 0, stream,
                       qh, kh, vt, (const unsigned long long*)mp, xh);
    hipLaunchKernelGGL(out_gemm_k, dim3(EE / 128, BB * SS / 128), dim3(256), 0, stream, xh, Wo, bo, out);
}

// Round 6
// 140.409 us; speedup vs baseline: 1.9499x; 1.9499x over previous
//
#include <hip/hip_runtime.h>

#define BB 2
#define SS 2048
#define EE 768
#define HH 12
#define DKK 64

typedef _Float16 h16;
typedef _Float16 half8 __attribute__((ext_vector_type(8)));
typedef _Float16 h16x4 __attribute__((ext_vector_type(4)));
typedef float f32x4 __attribute__((ext_vector_type(4)));

// ---------------- mask packing: int32 [S,S] -> 1 bit, word = 32 cols ----------------
__global__ void pack_mask_k(const int* __restrict__ mask, unsigned* __restrict__ mp) {
    int idx = blockIdx.x * 256 + threadIdx.x;      // 0 .. S*S/32-1
    int base = idx * 32;
    const int4* m4 = (const int4*)(mask + base);
    unsigned w = 0;
#pragma unroll
    for (int i = 0; i < 8; ++i) {
        int4 v = m4[i];
        if (v.x) w |= 1u << (i * 4 + 0);
        if (v.y) w |= 1u << (i * 4 + 1);
        if (v.z) w |= 1u << (i * 4 + 2);
        if (v.w) w |= 1u << (i * 4 + 3);
    }
    mp[idx] = w;
}

// ---------------- projection GEMM: k/q row-major [b,h,s,d]; v TRANSPOSED [b,h,d,s] ----------------
__launch_bounds__(256)
__global__ void proj_gemm_k(const float* __restrict__ srcK, const float* __restrict__ srcQ,
                            const float* __restrict__ srcV, const float* __restrict__ Wk,
                            const float* __restrict__ bk,
                            h16* __restrict__ kh, h16* __restrict__ qh, h16* __restrict__ vtp) {
    __shared__ h16 As[128 * 64];
    __shared__ h16 Bs[128 * 64];
    const int z = blockIdx.z;
    const float* src = (z == 0) ? srcK : ((z == 1) ? srcQ : srcV);
    const int n0 = blockIdx.x * 128, m0 = blockIdx.y * 128;
    const int tid = threadIdx.x, lane = tid & 63, wid = tid >> 6;
    const int wr = wid >> 1, wc = wid & 1;
    f32x4 acc[4][4] = {};

    for (int k0 = 0; k0 < EE; k0 += 64) {
#pragma unroll
        for (int it = 0; it < 4; ++it) {
            int e8 = it * 256 + tid;          // 0..1023 granules of 8 elems
            int row = e8 >> 3, g = e8 & 7;
            const float* pa = src + (m0 + row) * EE + k0 + g * 8;
            const float* pb = Wk + (n0 + row) * EE + k0 + g * 8;
            float4 a0 = *(const float4*)pa, a1 = *(const float4*)(pa + 4);
            float4 b0 = *(const float4*)pb, b1 = *(const float4*)(pb + 4);
            half8 ha = {(h16)a0.x, (h16)a0.y, (h16)a0.z, (h16)a0.w,
                        (h16)a1.x, (h16)a1.y, (h16)a1.z, (h16)a1.w};
            half8 hb = {(h16)b0.x, (h16)b0.y, (h16)b0.z, (h16)b0.w,
                        (h16)b1.x, (h16)b1.y, (h16)b1.z, (h16)b1.w};
            int sw = (g ^ (row & 7)) << 4;
            *(half8*)((char*)As + row * 128 + sw) = ha;
            *(half8*)((char*)Bs + row * 128 + sw) = hb;
        }
        __syncthreads();
#pragma unroll
        for (int ks = 0; ks < 2; ++ks) {
            half8 a[4], b[4];
#pragma unroll
            for (int rf = 0; rf < 4; ++rf) {
                int row = wr * 64 + rf * 16 + (lane & 15);
                int g = (ks * 4 + (lane >> 4)) ^ (row & 7);
                a[rf] = *(const half8*)((const char*)As + row * 128 + (g << 4));
            }
#pragma unroll
            for (int cf = 0; cf < 4; ++cf) {
                int row = wc * 64 + cf * 16 + (lane & 15);
                int g = (ks * 4 + (lane >> 4)) ^ (row & 7);
                b[cf] = *(const half8*)((const char*)Bs + row * 128 + (g << 4));
            }
#pragma unroll
            for (int rf = 0; rf < 4; ++rf)
#pragma unroll
                for (int cf = 0; cf < 4; ++cf)
                    acc[rf][cf] = __builtin_amdgcn_mfma_f32_16x16x32_f16(a[rf], b[cf], acc[rf][cf], 0, 0, 0);
        }
        __syncthreads();
    }
    if (z == 2) {
        // V: write transposed vt[(b*H+h)*64 + d][s], 4 consecutive s packed
#pragma unroll
        for (int rf = 0; rf < 4; ++rf)
#pragma unroll
            for (int cf = 0; cf < 4; ++cf) {
                int n = n0 + wc * 64 + cf * 16 + (lane & 15);
                float bias = bk[n];
                int h = n >> 6, d = n & 63;
                int mb = m0 + wr * 64 + rf * 16 + (lane >> 4) * 4;
                int b = mb >> 11, s = mb & 2047;
                h16x4 pv = {(h16)(acc[rf][cf][0] + bias), (h16)(acc[rf][cf][1] + bias),
                            (h16)(acc[rf][cf][2] + bias), (h16)(acc[rf][cf][3] + bias)};
                *(h16x4*)(vtp + ((long)((b * HH + h) * 64 + d)) * SS + s) = pv;
            }
    } else {
        h16* dst = (z == 0) ? kh : qh;
#pragma unroll
        for (int rf = 0; rf < 4; ++rf)
#pragma unroll
            for (int cf = 0; cf < 4; ++cf) {
                int n = n0 + wc * 64 + cf * 16 + (lane & 15);
                float bias = bk[n];
                int h = n >> 6, d = n & 63;
#pragma unroll
                for (int j = 0; j < 4; ++j) {
                    int m = m0 + wr * 64 + rf * 16 + (lane >> 4) * 4 + j;
                    int b = m >> 11, s = m & 2047;
                    dst[(((long)(b * HH + h) * SS + s) << 6) + d] = (h16)(acc[rf][cf][j] + bias);
                }
            }
    }
}

// ---------------- flash attention: 4 waves x 16 q-rows, LDS-staged K/V^T tiles ----------------
// LDS layout per tile: [64 rows][8 granules of 16B], slot gl of row r holds global
// granule gl ^ (r&7)  (involution swizzle -> conflict-free ds_read_b128 column reads)
struct StageRegs { half8 k[2], v[2]; };

__device__ __forceinline__ void ld_stage(StageRegs& r, const h16* __restrict__ kg,
                                         const h16* __restrict__ vg,
                                         int kv0, int wid, int lane) {
    int rr = lane >> 3;
    int sg = (lane & 7) ^ rr;                  // pre-swizzled global granule
#pragma unroll
    for (int i = 0; i < 2; ++i) {
        int row = wid * 16 + i * 8 + rr;       // row & 7 == rr
        r.k[i] = *(const half8*)(kg + (long)(kv0 + row) * DKK + sg * 8);
        r.v[i] = *(const half8*)(vg + (long)row * SS + kv0 + sg * 8);
    }
}

__device__ __forceinline__ void st_stage(h16* __restrict__ kl, h16* __restrict__ vl,
                                         const StageRegs& r, int wid, int lane) {
#pragma unroll
    for (int i = 0; i < 2; ++i) {              // linear store: lane*16B within wave chunk
        *(half8*)(kl + wid * 1024 + i * 512 + lane * 8) = r.k[i];
        *(half8*)(vl + wid * 1024 + i * 512 + lane * 8) = r.v[i];
    }
}

__launch_bounds__(256, 3)
__global__ void attn_k(const h16* __restrict__ qh, const h16* __restrict__ kh,
                       const h16* __restrict__ vt, const unsigned long long* __restrict__ mp,
                       h16* __restrict__ xh) {
    __shared__ h16 Kbuf[2][4096];
    __shared__ h16 Vbuf[2][4096];
    __shared__ char Ps[8192];                  // per-wave private 2KB P tile
    const int tid = threadIdx.x;
    const int lane = tid & 63, wid = tid >> 6;
    const int l = lane & 15, g = lane >> 4;
    // XCD-aware swizzle: 768 blocks; each XCD gets 96 consecutive idx = 3 whole heads
    const int bid = blockIdx.x;
    const int idx = (bid & 7) * 96 + (bid >> 3);
    const int q0 = (idx & 31) * 64 + wid * 16;
    const int bh = idx >> 5;
    const long base = (long)bh * SS * DKK;
    const h16* kg = kh + base;
    const h16* vg = vt + base;
    char* pbase = Ps + wid * 2048;

    half8 qf0, qf1;
    {
        const h16* qp = qh + base + (long)(q0 + l) * DKK + g * 8;
        qf0 = *(const half8*)qp;
        qf1 = *(const half8*)(qp + 32);
    }
    const unsigned long long* mrow = mp + (long)(q0 + l) * (SS / 64);

    f32x4 o[4] = {};
    float m2 = -INFINITY, lsum = 0.f;
    const float K2 = 8.0f * 1.44269504f;       // sqrt(dk) * log2(e)  (source multiplies!)
    const float C2 = 1e-6f * 1.44269504f;      // masked value in log2 domain

    StageRegs sr;
    ld_stage(sr, kg, vg, 0, wid, lane);        // tile 0
    st_stage(Kbuf[0], Vbuf[0], sr, wid, lane);
    __syncthreads();

    for (int t = 0; t < 32; ++t) {
        const h16* Kl = Kbuf[t & 1];
        const h16* Vl = Vbuf[t & 1];
        // ---- issue next tile's global loads early (T14 split) ----
        ld_stage(sr, kg, vg, ((t + 1) & 31) * 64, wid, lane);
        // ---- K fragments from LDS + QK^T ----
        half8 ka[4], kb[4];
#pragma unroll
        for (int cf = 0; cf < 4; ++cf) {
            int row = cf * 16 + l;
            const h16* kp = Kl + row * 64;
            ka[cf] = *(const half8*)(kp + ((g ^ (row & 7)) << 3));
            kb[cf] = *(const half8*)(kp + (((4 + g) ^ (row & 7)) << 3));
        }
        f32x4 s[4];
        __builtin_amdgcn_s_setprio(1);
#pragma unroll
        for (int cf = 0; cf < 4; ++cf) {
            f32x4 z = {};
            z = __builtin_amdgcn_mfma_f32_16x16x32_f16(ka[cf], qf0, z, 0, 0, 0);
            z = __builtin_amdgcn_mfma_f32_16x16x32_f16(kb[cf], qf1, z, 0, 0, 0);
            s[cf] = z;
        }
        __builtin_amdgcn_s_setprio(0);
        // ---- mask + scale into exp2 domain ----
        unsigned long long mw = mrow[t];
        unsigned w0 = (unsigned)mw, w1 = (unsigned)(mw >> 32);
#pragma unroll
        for (int cf = 0; cf < 4; ++cf) {
            unsigned wcb = (cf & 2) ? w1 : w0;
#pragma unroll
            for (int j = 0; j < 4; ++j) {
                unsigned sh = ((cf & 1) << 4) + g * 4 + j;
                s[cf][j] = ((wcb >> sh) & 1u) ? s[cf][j] * K2 : C2;
            }
        }
        // ---- online softmax (per-lane q; shfl-free fast path) ----
        float pmax = fmaxf(fmaxf(s[0][0], s[0][1]), fmaxf(s[0][2], s[0][3]));
#pragma unroll
        for (int cf = 1; cf < 4; ++cf)
            pmax = fmaxf(pmax, fmaxf(fmaxf(s[cf][0], s[cf][1]), fmaxf(s[cf][2], s[cf][3])));
        if (!__all(pmax <= m2 + 11.0f)) {      // defer-max (T13)
            pmax = fmaxf(pmax, __shfl_xor(pmax, 16));
            pmax = fmaxf(pmax, __shfl_xor(pmax, 32));
            float mnew = fmaxf(m2, pmax);
            float alpha = __builtin_amdgcn_exp2f(m2 - mnew);
#pragma unroll
            for (int df = 0; df < 4; ++df)
#pragma unroll
                for (int j = 0; j < 4; ++j) o[df][j] *= alpha;
            lsum *= alpha;
            m2 = mnew;
        }
        float rs = 0.f;
#pragma unroll
        for (int cf = 0; cf < 4; ++cf)
#pragma unroll
            for (int j = 0; j < 4; ++j) {
                float p = __builtin_amdgcn_exp2f(s[cf][j] - m2);
                s[cf][j] = p;
                rs += p;
            }
        lsum += rs;                            // per-lane partial; reduced in epilogue
        // ---- P^T -> per-wave LDS, packed b64 stores ----
#pragma unroll
        for (int cf = 0; cf < 4; ++cf) {
            h16x4 pk = {(h16)s[cf][0], (h16)s[cf][1], (h16)s[cf][2], (h16)s[cf][3]};
            int gran = (2 * cf + (g >> 1)) ^ (l & 7);
            *(h16x4*)(pbase + l * 128 + gran * 16 + (g & 1) * 8) = pk;
        }
        // ---- O^T += V^T · P^T (V frags from LDS per k-slice) ----
#pragma unroll
        for (int ks = 0; ks < 2; ++ks) {
            int gr = (ks * 4 + g) ^ (l & 7);
            half8 pf = *(const half8*)(pbase + l * 128 + gr * 16);
            half8 vk[4];
#pragma unroll
            for (int df = 0; df < 4; ++df) {
                int row = df * 16 + l;
                vk[df] = *(const half8*)(Vl + row * 64 + (((ks * 4 + g) ^ (row & 7)) << 3));
            }
            __builtin_amdgcn_s_setprio(1);
#pragma unroll
            for (int df = 0; df < 4; ++df)
                o[df] = __builtin_amdgcn_mfma_f32_16x16x32_f16(vk[df], pf, o[df], 0, 0, 0);
            __builtin_amdgcn_s_setprio(0);
        }
        // ---- write next tile to the other LDS buffer; one barrier per tile ----
        st_stage(Kbuf[(t + 1) & 1], Vbuf[(t + 1) & 1], sr, wid, lane);
        __syncthreads();
    }

    // epilogue: reduce lsum across the 4 g-groups; lane owns q = q0+l
    lsum += __shfl_xor(lsum, 16);
    lsum += __shfl_xor(lsum, 32);
    float inv = 1.0f / lsum;
    int b = bh / HH, h = bh % HH;
    h16* xp = xh + (long)(b * SS + q0 + l) * EE + h * 64 + g * 4;
#pragma unroll
    for (int df = 0; df < 4; ++df) {
        h16x4 v4 = {(h16)(o[df][0] * inv), (h16)(o[df][1] * inv),
                    (h16)(o[df][2] * inv), (h16)(o[df][3] * inv)};
        *(h16x4*)(xp + df * 16) = v4;
    }
}

// ---------------- output GEMM: out = x @ Wo^T + bo (fp32 out) ----------------
__launch_bounds__(256)
__global__ void out_gemm_k(const h16* __restrict__ xh, const float* __restrict__ Wo,
                           const float* __restrict__ bo, float* __restrict__ out) {
    __shared__ h16 As[128 * 64];
    __shared__ h16 Bs[128 * 64];
    const int n0 = blockIdx.x * 128, m0 = blockIdx.y * 128;
    const int tid = threadIdx.x, lane = tid & 63, wid = tid >> 6;
    const int wr = wid >> 1, wc = wid & 1;
    f32x4 acc[4][4] = {};

    for (int k0 = 0; k0 < EE; k0 += 64) {
#pragma unroll
        for (int it = 0; it < 4; ++it) {
            int e8 = it * 256 + tid;
            int row = e8 >> 3, g = e8 & 7;
            half8 ha = *(const half8*)(xh + (m0 + row) * EE + k0 + g * 8);
            const float* pb = Wo + (n0 + row) * EE + k0 + g * 8;
            float4 b0 = *(const float4*)pb, b1 = *(const float4*)(pb + 4);
            half8 hb = {(h16)b0.x, (h16)b0.y, (h16)b0.z, (h16)b0.w,
                        (h16)b1.x, (h16)b1.y, (h16)b1.z, (h16)b1.w};
            int sw = (g ^ (row & 7)) << 4;
            *(half8*)((char*)As + row * 128 + sw) = ha;
            *(half8*)((char*)Bs + row * 128 + sw) = hb;
        }
        __syncthreads();
#pragma unroll
        for (int ks = 0; ks < 2; ++ks) {
            half8 a[4], b[4];
#pragma unroll
            for (int rf = 0; rf < 4; ++rf) {
                int row = wr * 64 + rf * 16 + (lane & 15);
                int g = (ks * 4 + (lane >> 4)) ^ (row & 7);
                a[rf] = *(const half8*)((const char*)As + row * 128 + (g << 4));
            }
#pragma unroll
            for (int cf = 0; cf < 4; ++cf) {
                int row = wc * 64 + cf * 16 + (lane & 15);
                int g = (ks * 4 + (lane >> 4)) ^ (row & 7);
                b[cf] = *(const half8*)((const char*)Bs + row * 128 + (g << 4));
            }
#pragma unroll
            for (int rf = 0; rf < 4; ++rf)
#pragma unroll
                for (int cf = 0; cf < 4; ++cf)
                    acc[rf][cf] = __builtin_amdgcn_mfma_f32_16x16x32_f16(a[rf], b[cf], acc[rf][cf], 0, 0, 0);
        }
        __syncthreads();
    }
#pragma unroll
    for (int rf = 0; rf < 4; ++rf)
#pragma unroll
        for (int cf = 0; cf < 4; ++cf) {
            int n = n0 + wc * 64 + cf * 16 + (lane & 15);
            float bias = bo[n];
#pragma unroll
            for (int j = 0; j < 4; ++j) {
                int m = m0 + wr * 64 + rf * 16 + (lane >> 4) * 4 + j;
                out[(long)m * EE + n] = acc[rf][cf][j] + bias;
            }
        }
}

extern "C" void kernel_launch(void* const* d_in, const int* in_sizes, int n_in,
                              void* d_out, int out_size, void* d_ws, size_t ws_size,
                              hipStream_t stream) {
    const float* key   = (const float*)d_in[0];
    const float* query = (const float*)d_in[1];
    const float* value = (const float*)d_in[2];
    const int*   mask  = (const int*)d_in[3];
    const float* Wk    = (const float*)d_in[4];
    const float* bk    = (const float*)d_in[5];
    const float* Wo    = (const float*)d_in[6];
    const float* bo    = (const float*)d_in[7];

    char* ws = (char*)d_ws;
    h16* qh = (h16*)(ws + 0);
    h16* kh = (h16*)(ws + 6291456);
    h16* vt = (h16*)(ws + 12582912);
    h16* xh = (h16*)(ws + 18874368);
    unsigned* mp = (unsigned*)(ws + 25165824);
    float* out = (float*)d_out;

    hipLaunchKernelGGL(pack_mask_k, dim3(SS * SS / 32 / 256), dim3(256), 0, stream, mask, mp);
    hipLaunchKernelGGL(proj_gemm_k, dim3(EE / 128, BB * SS / 128, 3), dim3(256), 0, stream,
                       key, query, value, Wk, bk, kh, qh, vt);
    hipLaunchKernelGGL(attn_k, dim3(SS / 64 * BB * HH), dim3(256), 0, stream,
                       qh, kh, vt, (const unsigned long long*)mp, xh);
    hipLaunchKernelGGL(out_gemm_k, dim3(EE / 128, BB * SS / 128), dim3(256), 0, stream, xh, Wo, bo, out);
}

// Round 7
// 131.983 us; speedup vs baseline: 2.0743x; 1.0638x over previous
//
#include <hip/hip_runtime.h>

#define BB 2
#define SS 2048
#define EE 768
#define HH 12
#define DKK 64

typedef _Float16 h16;
typedef _Float16 half8 __attribute__((ext_vector_type(8)));
typedef _Float16 h16x4 __attribute__((ext_vector_type(4)));
typedef float f32x4 __attribute__((ext_vector_type(4)));

// ---------------- mask packing: int32 [S,S] -> 1 bit, word = 32 cols ----------------
__global__ void pack_mask_k(const int* __restrict__ mask, unsigned* __restrict__ mp) {
    int idx = blockIdx.x * 256 + threadIdx.x;      // 0 .. S*S/32-1
    int base = idx * 32;
    const int4* m4 = (const int4*)(mask + base);
    unsigned w = 0;
#pragma unroll
    for (int i = 0; i < 8; ++i) {
        int4 v = m4[i];
        if (v.x) w |= 1u << (i * 4 + 0);
        if (v.y) w |= 1u << (i * 4 + 1);
        if (v.z) w |= 1u << (i * 4 + 2);
        if (v.w) w |= 1u << (i * 4 + 3);
    }
    mp[idx] = w;
}

// ---------------- projection GEMM: k/q row-major [b,h,s,d]; v TRANSPOSED [b,h,d,s] ----------------
// 1-D grid of 576 blocks, XCD-swizzled: each XCD owns 12 consecutive m-stripes x 6 n of one z,
// so the 6 sharers of each src stripe hit the same L2 and Wk stays L2-resident.
__launch_bounds__(256)
__global__ void proj_gemm_k(const float* __restrict__ srcK, const float* __restrict__ srcQ,
                            const float* __restrict__ srcV, const float* __restrict__ Wk,
                            const float* __restrict__ bk,
                            h16* __restrict__ kh, h16* __restrict__ qh, h16* __restrict__ vtp) {
    __shared__ h16 As[128 * 64];
    __shared__ h16 Bs[128 * 64];
    const int bid = blockIdx.x;                     // 0..575
    const int idx = (bid & 7) * 72 + (bid >> 3);    // XCD-contiguous logical index
    const int z = idx / 192;
    const int rem = idx % 192;
    const int n0 = (rem % 6) * 128, m0 = (rem / 6) * 128;
    const float* src = (z == 0) ? srcK : ((z == 1) ? srcQ : srcV);
    const int tid = threadIdx.x, lane = tid & 63, wid = tid >> 6;
    const int wr = wid >> 1, wc = wid & 1;
    f32x4 acc[4][4] = {};

    for (int k0 = 0; k0 < EE; k0 += 64) {
#pragma unroll
        for (int it = 0; it < 4; ++it) {
            int e8 = it * 256 + tid;          // 0..1023 granules of 8 elems
            int row = e8 >> 3, g = e8 & 7;
            const float* pa = src + (m0 + row) * EE + k0 + g * 8;
            const float* pb = Wk + (n0 + row) * EE + k0 + g * 8;
            float4 a0 = *(const float4*)pa, a1 = *(const float4*)(pa + 4);
            float4 b0 = *(const float4*)pb, b1 = *(const float4*)(pb + 4);
            half8 ha = {(h16)a0.x, (h16)a0.y, (h16)a0.z, (h16)a0.w,
                        (h16)a1.x, (h16)a1.y, (h16)a1.z, (h16)a1.w};
            half8 hb = {(h16)b0.x, (h16)b0.y, (h16)b0.z, (h16)b0.w,
                        (h16)b1.x, (h16)b1.y, (h16)b1.z, (h16)b1.w};
            int sw = (g ^ (row & 7)) << 4;
            *(half8*)((char*)As + row * 128 + sw) = ha;
            *(half8*)((char*)Bs + row * 128 + sw) = hb;
        }
        __syncthreads();
#pragma unroll
        for (int ks = 0; ks < 2; ++ks) {
            half8 a[4], b[4];
#pragma unroll
            for (int rf = 0; rf < 4; ++rf) {
                int row = wr * 64 + rf * 16 + (lane & 15);
                int g = (ks * 4 + (lane >> 4)) ^ (row & 7);
                a[rf] = *(const half8*)((const char*)As + row * 128 + (g << 4));
            }
#pragma unroll
            for (int cf = 0; cf < 4; ++cf) {
                int row = wc * 64 + cf * 16 + (lane & 15);
                int g = (ks * 4 + (lane >> 4)) ^ (row & 7);
                b[cf] = *(const half8*)((const char*)Bs + row * 128 + (g << 4));
            }
#pragma unroll
            for (int rf = 0; rf < 4; ++rf)
#pragma unroll
                for (int cf = 0; cf < 4; ++cf)
                    acc[rf][cf] = __builtin_amdgcn_mfma_f32_16x16x32_f16(a[rf], b[cf], acc[rf][cf], 0, 0, 0);
        }
        __syncthreads();
    }
    if (z == 2) {
        // V: write transposed vt[(b*H+h)*64 + d][s], 4 consecutive s packed
#pragma unroll
        for (int rf = 0; rf < 4; ++rf)
#pragma unroll
            for (int cf = 0; cf < 4; ++cf) {
                int n = n0 + wc * 64 + cf * 16 + (lane & 15);
                float bias = bk[n];
                int h = n >> 6, d = n & 63;
                int mb = m0 + wr * 64 + rf * 16 + (lane >> 4) * 4;
                int b = mb >> 11, s = mb & 2047;
                h16x4 pv = {(h16)(acc[rf][cf][0] + bias), (h16)(acc[rf][cf][1] + bias),
                            (h16)(acc[rf][cf][2] + bias), (h16)(acc[rf][cf][3] + bias)};
                *(h16x4*)(vtp + ((long)((b * HH + h) * 64 + d)) * SS + s) = pv;
            }
    } else {
        h16* dst = (z == 0) ? kh : qh;
#pragma unroll
        for (int rf = 0; rf < 4; ++rf)
#pragma unroll
            for (int cf = 0; cf < 4; ++cf) {
                int n = n0 + wc * 64 + cf * 16 + (lane & 15);
                float bias = bk[n];
                int h = n >> 6, d = n & 63;
#pragma unroll
                for (int j = 0; j < 4; ++j) {
                    int m = m0 + wr * 64 + rf * 16 + (lane >> 4) * 4 + j;
                    int b = m >> 11, s = m & 2047;
                    dst[(((long)(b * HH + h) * SS + s) << 6) + d] = (h16)(acc[rf][cf][j] + bias);
                }
            }
    }
}

// ---------------- flash attention: 4 waves x 16 q-rows, LDS-staged K/V^T tiles ----------------
// LDS layout per tile: [64 rows][8 granules of 16B], slot gl of row r holds global
// granule gl ^ (r&7)  (involution swizzle -> conflict-free ds_read_b128 column reads)
struct StageRegs { half8 k[2], v[2]; };

__device__ __forceinline__ void ld_stage(StageRegs& r, const h16* __restrict__ kg,
                                         const h16* __restrict__ vg,
                                         int kv0, int wid, int lane) {
    int rr = lane >> 3;
    int sg = (lane & 7) ^ rr;                  // pre-swizzled global granule
#pragma unroll
    for (int i = 0; i < 2; ++i) {
        int row = wid * 16 + i * 8 + rr;       // row & 7 == rr
        r.k[i] = *(const half8*)(kg + (long)(kv0 + row) * DKK + sg * 8);
        r.v[i] = *(const half8*)(vg + (long)row * SS + kv0 + sg * 8);
    }
}

__device__ __forceinline__ void st_stage(h16* __restrict__ kl, h16* __restrict__ vl,
                                         const StageRegs& r, int wid, int lane) {
#pragma unroll
    for (int i = 0; i < 2; ++i) {              // linear store: lane*16B within wave chunk
        *(half8*)(kl + wid * 1024 + i * 512 + lane * 8) = r.k[i];
        *(half8*)(vl + wid * 1024 + i * 512 + lane * 8) = r.v[i];
    }
}

__launch_bounds__(256, 3)
__global__ void attn_k(const h16* __restrict__ qh, const h16* __restrict__ kh,
                       const h16* __restrict__ vt, const unsigned long long* __restrict__ mp,
                       h16* __restrict__ xh) {
    __shared__ h16 Kbuf[2][4096];
    __shared__ h16 Vbuf[2][4096];
    __shared__ char Ps[8192];                  // per-wave private 2KB P tile
    const int tid = threadIdx.x;
    const int lane = tid & 63, wid = tid >> 6;
    const int l = lane & 15, g = lane >> 4;
    // XCD-aware swizzle: 768 blocks; each XCD gets 96 consecutive idx = 3 whole heads
    const int bid = blockIdx.x;
    const int idx = (bid & 7) * 96 + (bid >> 3);
    const int q0 = (idx & 31) * 64 + wid * 16;
    const int bh = idx >> 5;
    const long base = (long)bh * SS * DKK;
    const h16* kg = kh + base;
    const h16* vg = vt + base;
    char* pbase = Ps + wid * 2048;

    half8 qf0, qf1;
    {
        const h16* qp = qh + base + (long)(q0 + l) * DKK + g * 8;
        qf0 = *(const half8*)qp;
        qf1 = *(const half8*)(qp + 32);
    }
    const unsigned long long* mrow = mp + (long)(q0 + l) * (SS / 64);

    f32x4 o[4] = {};
    float m2 = -INFINITY, lsum = 0.f;
    const float K2 = 8.0f * 1.44269504f;       // sqrt(dk) * log2(e)  (source multiplies!)
    const float C2 = 1e-6f * 1.44269504f;      // masked value in log2 domain

    StageRegs sr;
    ld_stage(sr, kg, vg, 0, wid, lane);        // tile 0
    st_stage(Kbuf[0], Vbuf[0], sr, wid, lane);
    __syncthreads();

    for (int t = 0; t < 32; ++t) {
        const h16* Kl = Kbuf[t & 1];
        const h16* Vl = Vbuf[t & 1];
        // ---- issue next tile's global loads early (T14 split) ----
        ld_stage(sr, kg, vg, ((t + 1) & 31) * 64, wid, lane);
        // ---- K fragments from LDS + QK^T ----
        half8 ka[4], kb[4];
#pragma unroll
        for (int cf = 0; cf < 4; ++cf) {
            int row = cf * 16 + l;
            const h16* kp = Kl + row * 64;
            ka[cf] = *(const half8*)(kp + ((g ^ (row & 7)) << 3));
            kb[cf] = *(const half8*)(kp + (((4 + g) ^ (row & 7)) << 3));
        }
        f32x4 s[4];
        __builtin_amdgcn_s_setprio(1);
#pragma unroll
        for (int cf = 0; cf < 4; ++cf) {
            f32x4 z = {};
            z = __builtin_amdgcn_mfma_f32_16x16x32_f16(ka[cf], qf0, z, 0, 0, 0);
            z = __builtin_amdgcn_mfma_f32_16x16x32_f16(kb[cf], qf1, z, 0, 0, 0);
            s[cf] = z;
        }
        __builtin_amdgcn_s_setprio(0);
        // ---- mask + scale into exp2 domain ----
        unsigned long long mw = mrow[t];
        unsigned w0 = (unsigned)mw, w1 = (unsigned)(mw >> 32);
#pragma unroll
        for (int cf = 0; cf < 4; ++cf) {
            unsigned wcb = (cf & 2) ? w1 : w0;
#pragma unroll
            for (int j = 0; j < 4; ++j) {
                unsigned sh = ((cf & 1) << 4) + g * 4 + j;
                s[cf][j] = ((wcb >> sh) & 1u) ? s[cf][j] * K2 : C2;
            }
        }
        // ---- online softmax (per-lane q; shfl-free fast path) ----
        float pmax = fmaxf(fmaxf(s[0][0], s[0][1]), fmaxf(s[0][2], s[0][3]));
#pragma unroll
        for (int cf = 1; cf < 4; ++cf)
            pmax = fmaxf(pmax, fmaxf(fmaxf(s[cf][0], s[cf][1]), fmaxf(s[cf][2], s[cf][3])));
        if (!__all(pmax <= m2 + 11.0f)) {      // defer-max (T13)
            pmax = fmaxf(pmax, __shfl_xor(pmax, 16));
            pmax = fmaxf(pmax, __shfl_xor(pmax, 32));
            float mnew = fmaxf(m2, pmax);
            float alpha = __builtin_amdgcn_exp2f(m2 - mnew);
#pragma unroll
            for (int df = 0; df < 4; ++df)
#pragma unroll
                for (int j = 0; j < 4; ++j) o[df][j] *= alpha;
            lsum *= alpha;
            m2 = mnew;
        }
        float rs = 0.f;
#pragma unroll
        for (int cf = 0; cf < 4; ++cf)
#pragma unroll
            for (int j = 0; j < 4; ++j) {
                float p = __builtin_amdgcn_exp2f(s[cf][j] - m2);
                s[cf][j] = p;
                rs += p;
            }
        lsum += rs;                            // per-lane partial; reduced in epilogue
        // ---- P^T -> per-wave LDS, packed b64 stores ----
#pragma unroll
        for (int cf = 0; cf < 4; ++cf) {
            h16x4 pk = {(h16)s[cf][0], (h16)s[cf][1], (h16)s[cf][2], (h16)s[cf][3]};
            int gran = (2 * cf + (g >> 1)) ^ (l & 7);
            *(h16x4*)(pbase + l * 128 + gran * 16 + (g & 1) * 8) = pk;
        }
        // ---- O^T += V^T · P^T (V frags from LDS per k-slice) ----
#pragma unroll
        for (int ks = 0; ks < 2; ++ks) {
            int gr = (ks * 4 + g) ^ (l & 7);
            half8 pf = *(const half8*)(pbase + l * 128 + gr * 16);
            half8 vk[4];
#pragma unroll
            for (int df = 0; df < 4; ++df) {
                int row = df * 16 + l;
                vk[df] = *(const half8*)(Vl + row * 64 + (((ks * 4 + g) ^ (row & 7)) << 3));
            }
            __builtin_amdgcn_s_setprio(1);
#pragma unroll
            for (int df = 0; df < 4; ++df)
                o[df] = __builtin_amdgcn_mfma_f32_16x16x32_f16(vk[df], pf, o[df], 0, 0, 0);
            __builtin_amdgcn_s_setprio(0);
        }
        // ---- write next tile to the other LDS buffer; one barrier per tile ----
        st_stage(Kbuf[(t + 1) & 1], Vbuf[(t + 1) & 1], sr, wid, lane);
        __syncthreads();
    }

    // epilogue: reduce lsum across the 4 g-groups; lane owns q = q0+l
    lsum += __shfl_xor(lsum, 16);
    lsum += __shfl_xor(lsum, 32);
    float inv = 1.0f / lsum;
    int b = bh / HH, h = bh % HH;
    h16* xp = xh + (long)(b * SS + q0 + l) * EE + h * 64 + g * 4;
#pragma unroll
    for (int df = 0; df < 4; ++df) {
        h16x4 v4 = {(h16)(o[df][0] * inv), (h16)(o[df][1] * inv),
                    (h16)(o[df][2] * inv), (h16)(o[df][3] * inv)};
        *(h16x4*)(xp + df * 16) = v4;
    }
}

// ---------------- output GEMM: out = x @ Wo^T + bo (fp32 out) ----------------
// 1-D grid of 192 blocks, XCD-swizzled: each XCD owns 4 m-stripes x 6 n.
__launch_bounds__(256)
__global__ void out_gemm_k(const h16* __restrict__ xh, const float* __restrict__ Wo,
                           const float* __restrict__ bo, float* __restrict__ out) {
    __shared__ h16 As[128 * 64];
    __shared__ h16 Bs[128 * 64];
    const int bid = blockIdx.x;                    // 0..191
    const int idx = (bid & 7) * 24 + (bid >> 3);
    const int n0 = (idx % 6) * 128, m0 = (idx / 6) * 128;
    const int tid = threadIdx.x, lane = tid & 63, wid = tid >> 6;
    const int wr = wid >> 1, wc = wid & 1;
    f32x4 acc[4][4] = {};

    for (int k0 = 0; k0 < EE; k0 += 64) {
#pragma unroll
        for (int it = 0; it < 4; ++it) {
            int e8 = it * 256 + tid;
            int row = e8 >> 3, g = e8 & 7;
            half8 ha = *(const half8*)(xh + (m0 + row) * EE + k0 + g * 8);
            const float* pb = Wo + (n0 + row) * EE + k0 + g * 8;
            float4 b0 = *(const float4*)pb, b1 = *(const float4*)(pb + 4);
            half8 hb = {(h16)b0.x, (h16)b0.y, (h16)b0.z, (h16)b0.w,
                        (h16)b1.x, (h16)b1.y, (h16)b1.z, (h16)b1.w};
            int sw = (g ^ (row & 7)) << 4;
            *(half8*)((char*)As + row * 128 + sw) = ha;
            *(half8*)((char*)Bs + row * 128 + sw) = hb;
        }
        __syncthreads();
#pragma unroll
        for (int ks = 0; ks < 2; ++ks) {
            half8 a[4], b[4];
#pragma unroll
            for (int rf = 0; rf < 4; ++rf) {
                int row = wr * 64 + rf * 16 + (lane & 15);
                int g = (ks * 4 + (lane >> 4)) ^ (row & 7);
                a[rf] = *(const half8*)((const char*)As + row * 128 + (g << 4));
            }
#pragma unroll
            for (int cf = 0; cf < 4; ++cf) {
                int row = wc * 64 + cf * 16 + (lane & 15);
                int g = (ks * 4 + (lane >> 4)) ^ (row & 7);
                b[cf] = *(const half8*)((const char*)Bs + row * 128 + (g << 4));
            }
#pragma unroll
            for (int rf = 0; rf < 4; ++rf)
#pragma unroll
                for (int cf = 0; cf < 4; ++cf)
                    acc[rf][cf] = __builtin_amdgcn_mfma_f32_16x16x32_f16(a[rf], b[cf], acc[rf][cf], 0, 0, 0);
        }
        __syncthreads();
    }
#pragma unroll
    for (int rf = 0; rf < 4; ++rf)
#pragma unroll
        for (int cf = 0; cf < 4; ++cf) {
            int n = n0 + wc * 64 + cf * 16 + (lane & 15);
            float bias = bo[n];
#pragma unroll
            for (int j = 0; j < 4; ++j) {
                int m = m0 + wr * 64 + rf * 16 + (lane >> 4) * 4 + j;
                out[(long)m * EE + n] = acc[rf][cf][j] + bias;
            }
        }
}

extern "C" void kernel_launch(void* const* d_in, const int* in_sizes, int n_in,
                              void* d_out, int out_size, void* d_ws, size_t ws_size,
                              hipStream_t stream) {
    const float* key   = (const float*)d_in[0];
    const float* query = (const float*)d_in[1];
    const float* value = (const float*)d_in[2];
    const int*   mask  = (const int*)d_in[3];
    const float* Wk    = (const float*)d_in[4];
    const float* bk    = (const float*)d_in[5];
    const float* Wo    = (const float*)d_in[6];
    const float* bo    = (const float*)d_in[7];

    char* ws = (char*)d_ws;
    h16* qh = (h16*)(ws + 0);
    h16* kh = (h16*)(ws + 6291456);
    h16* vt = (h16*)(ws + 12582912);
    h16* xh = (h16*)(ws + 18874368);
    unsigned* mp = (unsigned*)(ws + 25165824);
    float* out = (float*)d_out;

    hipLaunchKernelGGL(pack_mask_k, dim3(SS * SS / 32 / 256), dim3(256), 0, stream, mask, mp);
    hipLaunchKernelGGL(proj_gemm_k, dim3(576), dim3(256), 0, stream,
                       key, query, value, Wk, bk, kh, qh, vt);
    hipLaunchKernelGGL(attn_k, dim3(SS / 64 * BB * HH), dim3(256), 0, stream,
                       qh, kh, vt, (const unsigned long long*)mp, xh);
    hipLaunchKernelGGL(out_gemm_k, dim3(192), dim3(256), 0, stream, xh, Wo, bo, out);
}